// Round 1
// baseline (125.691 us; speedup 1.0000x reference)
//
#include <hip/hip_runtime.h>

#define NROWS 8192
#define KDIM  512
#define NT    64                 // 8192/128 tiles per dim
#define NBLK  (NT*(NT+1)/2)      // upper-triangle tile pairs = 2080
#define SCL1  0x7F7F7F7F         // E8M0 scale bytes = 2^0 = 1.0
#define STRIP4 8192              // 32 rows x 512 k x 0.5 B per strip
#define C2    0.0144269504f      // log2(e)/100

typedef __attribute__((ext_vector_type(16))) float f32x16;
typedef __attribute__((ext_vector_type(4))) int i32x4;
typedef __attribute__((ext_vector_type(8))) int i32x8;

// async global->LDS, 16B per lane; dest is wave-uniform base + lane*16 (HW rule)
#define GLDS(g, l) __builtin_amdgcn_global_load_lds( \
    (const __attribute__((address_space(1))) void*)(g), \
    (__attribute__((address_space(3))) void*)(l), 16, 0, 0)

__device__ __forceinline__ i32x8 mk_op4(i32x4 lo) {
    i32x8 r;
    r[0] = lo[0]; r[1] = lo[1]; r[2] = lo[2]; r[3] = lo[3];
    r[4] = 0; r[5] = 0; r[6] = 0; r[7] = 0;   // fp4 uses only first 4 dwords
    return r;
}

// nearest e2m1 (scale 1.0) code for |x|: {0,0.5,1,1.5,2,3,4,6}
__device__ __forceinline__ int fp4_code(float x) {
    float v = fabsf(x);
    int c = v < 0.25f ? 0 : v < 0.75f ? 1 : v < 1.25f ? 2 : v < 1.75f ? 3
          : v < 2.5f  ? 4 : v < 3.5f  ? 5 : v < 5.0f  ? 6 : 7;
    return c | (x < 0.f ? 8 : 0);
}

// z (fp32) -> fp4 e2m1 in MFMA-operand order (unchanged — bitwise identical zb4/nq).
// Also zeroes the gram completion counter (workspace is re-poisoned every iter).
__global__ __launch_bounds__(256) void prep_kernel(const float* __restrict__ z,
                                                   unsigned char* __restrict__ zb4,
                                                   float* __restrict__ nq,
                                                   int* __restrict__ cnt) {
    if (blockIdx.x == 0 && threadIdx.x == 0) *cnt = 0;
    int wave = threadIdx.x >> 6, lane = threadIdx.x & 63;
    int row = blockIdx.x * 4 + wave;
    const float* zr = z + (size_t)row * KDIM + lane * 8;
    float4 v0 = *(const float4*)zr;
    float4 v1 = *(const float4*)(zr + 4);
    float vals[8] = {v0.x, v0.y, v0.z, v0.w, v1.x, v1.y, v1.z, v1.w};
    float s = 0.f;
    unsigned int pk = 0u;
#pragma unroll
    for (int i = 0; i < 8; ++i) {
        s += vals[i] * vals[i];
        pk |= (unsigned int)fp4_code(vals[i]) << (4 * i);   // nibble i = k0+i
    }
    int strip = row >> 5, lr = row & 31;
    size_t addr = (size_t)strip * STRIP4 + (lane >> 3) * 1024 +
                  ((lane >> 2) & 1) * 512 + lr * 16 + (lane & 3) * 4;
    *(unsigned int*)(zb4 + addr) = pk;
#pragma unroll
    for (int off = 32; off; off >>= 1) s += __shfl_down(s, off);
    if (lane == 0) nq[row] = -C2 * s;
}

// 128x128 Gram tile per block, 64x64 per wave (2x2 32x32x64 MX-fp4 MFMA).
// NEW: A+B strips (64 KB) staged once into LDS via global_load_lds (byte-copy of
// zb4, so all MFMA operand values and accumulation order are bitwise unchanged).
// L2 operand traffic halves: 266 MB -> 133 MB (the 2x2 wave grid's duplicate
// A/B fetches now hit LDS). ds_read_b128 of contiguous 16B/lane = conflict-free.
// NEW: deterministic last-block final reduction (agent-scope atomics) replaces
// the separate reduce_kernel launch; summation order identical to the old kernel.
__global__ __launch_bounds__(256, 2) void gram_kernel(const unsigned char* __restrict__ zb4,
                                                      const float* __restrict__ nq,
                                                      float* __restrict__ part,
                                                      int* __restrict__ cnt,
                                                      float* __restrict__ out) {
    __shared__ unsigned char lds[65536];     // [0,32K) = A strips, [32K,64K) = B strips
    __shared__ float wsum[4];
    __shared__ int lastFlag;

    int tid = threadIdx.x;
    int wave = tid >> 6, lane = tid & 63;
    int ln31 = lane & 31, kh = lane >> 5;
    int wm = wave >> 1, wn = wave & 1;

    // linear block id -> (bi, bj), bi <= bj
    int rem = blockIdx.x, bi = 0;
    while (rem >= NT - bi) { rem -= NT - bi; ++bi; }
    int bj = bi + rem;
    int rot = blockIdx.x & 7;

    // ---- stage A (4 strips, 32 KB) + B (4 strips, 32 KB) into LDS ----
    const unsigned char* srcA = zb4 + (size_t)(bi * 4) * STRIP4;
    const unsigned char* srcB = zb4 + (size_t)(bj * 4) * STRIP4;
    {
        int lo = tid * 16;                    // per-lane src offset within 4 KB chunk
        int wbase = wave * 1024;              // wave-uniform LDS dest within chunk
#pragma unroll
        for (int i = 0; i < 8; ++i)
            GLDS(srcA + i * 4096 + lo, lds + i * 4096 + wbase);
#pragma unroll
        for (int i = 0; i < 8; ++i)
            GLDS(srcB + i * 4096 + lo, lds + 32768 + i * 4096 + wbase);
    }

    int laneOff = kh * 512 + ln31 * 16;
    const unsigned char* pA0 = lds + (wm * 2) * STRIP4 + laneOff;
    const unsigned char* pA1 = pA0 + STRIP4;
    const unsigned char* pB0 = lds + 32768 + (wn * 2) * STRIP4 + laneOff;
    const unsigned char* pB1 = pB0 + STRIP4;

    f32x16 accf[2][2];
#pragma unroll
    for (int mi = 0; mi < 2; ++mi)
#pragma unroll
        for (int ni = 0; ni < 2; ++ni)
#pragma unroll
            for (int r = 0; r < 16; ++r) accf[mi][ni][r] = 0.f;

    __syncthreads();                          // drains vmcnt: staged data ready

#pragma unroll
    for (int ks = 0; ks < 8; ++ks) {
        int off = ((ks + rot) & 7) * 1024;   // rotated k-slice (same fp32 acc order)
        i32x8 a0 = mk_op4(*(const i32x4*)(pA0 + off));
        i32x8 a1 = mk_op4(*(const i32x4*)(pA1 + off));
        i32x8 b0 = mk_op4(*(const i32x4*)(pB0 + off));
        i32x8 b1 = mk_op4(*(const i32x4*)(pB1 + off));
        // cbsz=4 (A=fp4), blgp=4 (B=fp4), scales = 1.0
        accf[0][0] = __builtin_amdgcn_mfma_scale_f32_32x32x64_f8f6f4(a0, b0, accf[0][0], 4, 4, 0, SCL1, 0, SCL1);
        accf[0][1] = __builtin_amdgcn_mfma_scale_f32_32x32x64_f8f6f4(a0, b1, accf[0][1], 4, 4, 0, SCL1, 0, SCL1);
        accf[1][0] = __builtin_amdgcn_mfma_scale_f32_32x32x64_f8f6f4(a1, b0, accf[1][0], 4, 4, 0, SCL1, 0, SCL1);
        accf[1][1] = __builtin_amdgcn_mfma_scale_f32_32x32x64_f8f6f4(a1, b1, accf[1][1], 4, 4, 0, SCL1, 0, SCL1);
    }

    // ---- fused epilogue: exp2( min( s*2C2 + nq_i + nq_j, 0 ) ) ----
    int rowBase = bi * 128 + wm * 64;
    int colBase = bj * 128 + wn * 64;
    float nqj[2] = { nq[colBase + ln31], nq[colBase + 32 + ln31] };

    float local = 0.f;
    if (bi != bj) {
#pragma unroll
        for (int mi = 0; mi < 2; ++mi) {
#pragma unroll
            for (int reg = 0; reg < 16; ++reg) {
                int rowf = (reg & 3) + 8 * (reg >> 2) + 4 * kh;
                float nqi = nq[rowBase + mi * 32 + rowf];
#pragma unroll
                for (int ni = 0; ni < 2; ++ni) {
                    float arg = fmaf(accf[mi][ni][reg], 2.f * C2, nqi + nqj[ni]);
                    local += __builtin_exp2f(fminf(arg, 0.f));
                }
            }
        }
    } else {
#pragma unroll
        for (int mi = 0; mi < 2; ++mi) {
#pragma unroll
            for (int reg = 0; reg < 16; ++reg) {
                int rowf = (reg & 3) + 8 * (reg >> 2) + 4 * kh;
                int gi = rowBase + mi * 32 + rowf;
                float nqi = nq[gi];
#pragma unroll
                for (int ni = 0; ni < 2; ++ni) {
                    int gj = colBase + ni * 32 + ln31;
                    float arg = fmaf(accf[mi][ni][reg], 2.f * C2, nqi + nqj[ni]);
                    float e = __builtin_exp2f(fminf(arg, 0.f));
                    local += (gi < gj) ? e : 0.f;
                }
            }
        }
    }

#pragma unroll
    for (int off = 32; off; off >>= 1) local += __shfl_down(local, off);
    if (lane == 0) wsum[wave] = local;
    __syncthreads();

    // ---- publish partial + deterministic last-block final reduction ----
    if (tid == 0) {
        float val = wsum[0] + wsum[1] + wsum[2] + wsum[3];
        __hip_atomic_store(&part[blockIdx.x], val, __ATOMIC_RELEASE,
                           __HIP_MEMORY_SCOPE_AGENT);
        int old = __hip_atomic_fetch_add(cnt, 1, __ATOMIC_ACQ_REL,
                                         __HIP_MEMORY_SCOPE_AGENT);
        lastFlag = (old == NBLK - 1);
    }
    __syncthreads();

    if (lastFlag) {   // uniform across block; replicates old reduce_kernel exactly
        float s = 0.f;
        for (int i = tid; i < NBLK; i += 256)
            s += __hip_atomic_load(&part[i], __ATOMIC_RELAXED,
                                   __HIP_MEMORY_SCOPE_AGENT);
#pragma unroll
        for (int off = 32; off; off >>= 1) s += __shfl_down(s, off);
        if (lane == 0) wsum[wave] = s;
        __syncthreads();
        if (tid == 0) {
            float total = 2.f * (wsum[0] + wsum[1] + wsum[2] + wsum[3]);
            out[0] = logf(total / ((float)NROWS * (float)(NROWS - 1)));
        }
    }
}

extern "C" void kernel_launch(void* const* d_in, const int* in_sizes, int n_in,
                              void* d_out, int out_size, void* d_ws, size_t ws_size,
                              hipStream_t stream) {
    const float* z = (const float*)d_in[0];
    float* out = (float*)d_out;
    unsigned char* zb4 = (unsigned char*)d_ws;                    // 2 MB fp4, operand order
    float* nq = (float*)((char*)d_ws + (size_t)NROWS * KDIM / 2); // 32 KB
    float* part = nq + NROWS;                                     // 2080 floats
    int* cnt = (int*)(part + NBLK);                               // completion counter

    prep_kernel<<<NROWS / 4, 256, 0, stream>>>(z, zb4, nq, cnt);
    gram_kernel<<<NBLK, 256, 0, stream>>>(zb4, nq, part, cnt, out);
}